// Round 9
// baseline (520.420 us; speedup 1.0000x reference)
//
#include <hip/hip_runtime.h>
#include <stdint.h>

// ---------- types ----------
typedef unsigned short u16;
typedef u16   u16x4 __attribute__((ext_vector_type(4)));
typedef u16   u16x8 __attribute__((ext_vector_type(8)));
typedef float f32x4 __attribute__((ext_vector_type(4)));
typedef __bf16 bf16x8 __attribute__((ext_vector_type(8)));

// ---------- constants ----------
#define BB    16
#define NN    3136
#define CC    576
#define HEADS 8
#define HD    72
#define AGN   49
#define NTOT  1728
#define NCH   6                      // stageA chunks: tiles {9,8,8,8,8,8} of 64 tokens -> 768 blocks = 3/CU
#define SCALE 0.1178511301977579f   // 72^-0.5

__device__ __forceinline__ u16 f2bf(float f) {
    unsigned u = __float_as_uint(f);
    return (u16)((u + 0x7fffu + ((u >> 16) & 1u)) >> 16);
}
__device__ __forceinline__ float bf2f(u16 u) {
    return __uint_as_float(((unsigned)u) << 16);
}

// ---------- cast x -> bf16 ----------
__global__ __launch_bounds__(256) void k_cast_x(const float* __restrict__ x, u16* __restrict__ xb) {
    size_t i = (size_t)blockIdx.x * 256 + threadIdx.x;
    f32x4 v = *(const f32x4*)(x + i * 4);
    u16x4 o; o[0] = f2bf(v[0]); o[1] = f2bf(v[1]); o[2] = f2bf(v[2]); o[3] = f2bf(v[3]);
    *(u16x4*)(xb + i * 4) = o;
}

// ---------- pack transposed bf16 weights ----------
__global__ __launch_bounds__(256) void k_prep_w(const float* __restrict__ Wq, const float* __restrict__ Wkv,
                                                const float* __restrict__ Wp,
                                                u16* __restrict__ wbT, u16* __restrict__ wpT) {
    int idx = blockIdx.x * 256 + threadIdx.x;
    if (idx < NTOT * CC) {
        int nn = idx / CC, kk = idx % CC;
        float v = (nn < CC) ? Wq[kk * CC + nn] : Wkv[kk * (2 * CC) + (nn - CC)];
        wbT[idx] = f2bf(v);
    } else {
        int j = idx - NTOT * CC;
        int nn = j / CC, kk = j % CC;
        wpT[j] = f2bf(Wp[kk * CC + nn]);
    }
}

// ---------- jax.image.resize 'linear' 7x7 -> 56x56 ----------
__device__ __forceinline__ float bilerp7(const float* __restrict__ g, int oy, int ox) {
    float cy = (oy - 3.5f) * 0.125f;
    float cx = (ox - 3.5f) * 0.125f;
    float fy0 = floorf(cy), fx0 = floorf(cx);
    float ty = cy - fy0, tx = cx - fx0;
    int iy0 = (int)fy0, ix0 = (int)fx0;
    int y0 = min(6, max(0, iy0)), y1 = min(6, max(0, iy0 + 1));
    int x0 = min(6, max(0, ix0)), x1 = min(6, max(0, ix0 + 1));
    float g00 = g[y0 * 7 + x0], g01 = g[y0 * 7 + x1];
    float g10 = g[y1 * 7 + x0], g11 = g[y1 * 7 + x1];
    return (1.f - ty) * ((1.f - tx) * g00 + tx * g01) + ty * ((1.f - tx) * g10 + tx * g11);
}

// bias1 layout: [h][n][49]
__global__ __launch_bounds__(256) void k_bias1(const float* __restrict__ an, const float* __restrict__ ah,
                                               const float* __restrict__ aw, float* __restrict__ b1) {
    int idx = blockIdx.x * 256 + threadIdx.x;
    int ag = idx % AGN; int r = idx / AGN; int n = r % NN; int h = r / NN;
    int y = n / 56, x = n % 56;
    float v = bilerp7(an + (h * AGN + ag) * 49, y, x);
    b1[idx] = v + ah[(h * AGN + ag) * 56 + y] + aw[(h * AGN + ag) * 56 + x];
}

// bias2 layout: [h][n][64] f32, pad ag>=49 with -1e30 (softmax kills them)
__global__ __launch_bounds__(256) void k_bias2(const float* __restrict__ na, const float* __restrict__ ha,
                                               const float* __restrict__ wa, float* __restrict__ b2p) {
    int idx = blockIdx.x * 256 + threadIdx.x;
    int ag = idx & 63; int r = idx >> 6; int n = r % NN; int h = r / NN;
    float v;
    if (ag < AGN) {
        int y = n / 56, x = n % 56;
        v = bilerp7(na + (h * AGN + ag) * 49, y, x)
          + ha[(h * 56 + y) * AGN + ag] + wa[(h * 56 + x) * AGN + ag];
    } else v = -1e30f;
    b2p[idx] = v;
}

// ---------- MFMA GEMM: A[M x 576] @ Bt[NB x 576]^T,  BM=128 BN=128 BK=64, XCD-swizzled ----------
// MODE 0: bf16 scatter to Qp/Kp/Vp (direct scatter; L2 write-combining absorbs it — LDS variant was slower)
// MODE 1: f32+bias to Cf; MODE 2: f32 to Cf  -- via LDS-coalesced f32 epilogue
template<int MODE>
__global__ __launch_bounds__(256) void k_gemm(const u16* __restrict__ A, const u16* __restrict__ Bt,
                                              u16* __restrict__ Qp, u16* __restrict__ Kp, u16* __restrict__ Vp,
                                              float* __restrict__ Cf, const float* __restrict__ bias,
                                              const int M) {
    const int NB = (MODE == 0) ? NTOT : CC;
    __shared__ u16 SMEM[2 * 128 * 64];
    u16* Asm = SMEM;
    u16* Bsm = SMEM + 128 * 64;
    const int t = threadIdx.x, lane = t & 63, wid = t >> 6;
    const int wm = wid & 1, wn = wid >> 1;
    const int nwg = gridDim.x * gridDim.y;
    const int id = blockIdx.y * gridDim.x + blockIdx.x;
    const int qq = nwg >> 3, rr = nwg & 7;
    const int xcd = id & 7, off = id >> 3;
    const int nid = (xcd < rr ? xcd * (qq + 1) : rr * (qq + 1) + (xcd - rr) * qq) + off;
    const int row0 = (nid / gridDim.x) * 128, col0 = (nid % gridDim.x) * 128;
    const int lr = lane & 15, lk = lane >> 4;
    f32x4 acc[4][4];
#pragma unroll
    for (int m = 0; m < 4; m++)
#pragma unroll
        for (int n2 = 0; n2 < 4; n2++) acc[m][n2] = (f32x4)0.f;

    for (int kt = 0; kt < 9; ++kt) {
        const int k0 = kt * 64;
#pragma unroll
        for (int it = 0; it < 4; ++it) {
            int flat = it * 256 + wid * 64 + lane;
            int r = flat >> 3, lc = (flat & 7) ^ (r & 7);
            int arow = min(row0 + r, M - 1);
            const u16* src = A + (size_t)arow * CC + k0 + lc * 8;
            __builtin_amdgcn_global_load_lds((const __attribute__((address_space(1))) void*)src,
                                             (__attribute__((address_space(3))) void*)(&Asm[(it * 256 + wid * 64) * 8]),
                                             16, 0, 0);
        }
#pragma unroll
        for (int it = 0; it < 4; ++it) {
            int flat = it * 256 + wid * 64 + lane;
            int r = flat >> 3, lc = (flat & 7) ^ (r & 7);
            int brow = min(col0 + r, NB - 1);
            const u16* src = Bt + (size_t)brow * CC + k0 + lc * 8;
            __builtin_amdgcn_global_load_lds((const __attribute__((address_space(1))) void*)src,
                                             (__attribute__((address_space(3))) void*)(&Bsm[(it * 256 + wid * 64) * 8]),
                                             16, 0, 0);
        }
        __syncthreads();
#pragma unroll
        for (int kk = 0; kk < 2; ++kk) {
            const int klocal2 = (kk * 32 + lk * 8) * 2;
            bf16x8 av[4], bv[4];
#pragma unroll
            for (int m = 0; m < 4; m++) {
                int row = wm * 64 + m * 16 + lr;
                av[m] = *(const bf16x8*)((const char*)Asm + row * 128 + (klocal2 ^ ((row & 7) << 4)));
            }
#pragma unroll
            for (int n2 = 0; n2 < 4; n2++) {
                int row = wn * 64 + n2 * 16 + lr;
                bv[n2] = *(const bf16x8*)((const char*)Bsm + row * 128 + (klocal2 ^ ((row & 7) << 4)));
            }
#pragma unroll
            for (int m = 0; m < 4; m++)
#pragma unroll
                for (int n2 = 0; n2 < 4; n2++)
                    acc[m][n2] = __builtin_amdgcn_mfma_f32_16x16x32_bf16(av[m], bv[n2], acc[m][n2], 0, 0, 0);
        }
        __syncthreads();
    }

    if (MODE == 0) {
#pragma unroll
        for (int n2 = 0; n2 < 4; n2++) {
            int cgl = col0 + wn * 64 + n2 * 16 + lr;
            if (cgl >= NB) continue;
            int which = cgl / 576;
            int rem = cgl - which * 576;
            int hh = rem / 72;
            int dd = rem - hh * 72;
            u16* dst = which == 0 ? Qp : (which == 1 ? Kp : Vp);
#pragma unroll
            for (int m = 0; m < 4; m++)
#pragma unroll
                for (int j = 0; j < 4; j++) {
                    int rgl = row0 + wm * 64 + m * 16 + lk * 4 + j;
                    int b = rgl / NN, n = rgl - b * NN;
                    dst[((size_t)(b * 8 + hh) * NN + n) * 72 + dd] = f2bf(acc[m][n2][j]);
                }
        }
    } else {
        float* Ef = (float*)SMEM;
#pragma unroll
        for (int ph = 0; ph < 4; ++ph) {
            if (wm == (ph >> 1)) {
#pragma unroll
                for (int mm = 0; mm < 2; mm++) {
                    int m = (ph & 1) * 2 + mm;
#pragma unroll
                    for (int n2 = 0; n2 < 4; n2++) {
                        int col = wn * 64 + n2 * 16 + lr;
                        float addv = (MODE == 1) ? bias[min(col0 + col, NB - 1)] : 0.f;
#pragma unroll
                        for (int j = 0; j < 4; j++)
                            Ef[(mm * 16 + lk * 4 + j) * 136 + col] = acc[m][n2][j] + addv;
                    }
                }
            }
            __syncthreads();
#pragma unroll
            for (int cc2 = 0; cc2 < 4; ++cc2) {
                int cidx = cc2 * 256 + t;
                int rl = cidx >> 5, colc = cidx & 31;
                int cgl = col0 + colc * 4;
                int rgl = row0 + ph * 32 + rl;
                if (cgl < NB && rgl < M) {
                    f32x4 v = *(const f32x4*)&Ef[rl * 136 + colc * 4];
                    *(f32x4*)(Cf + (size_t)rgl * 576 + cgl) = v;
                }
            }
            __syncthreads();
        }
    }
}

// ---------- pool x (8x8 windows) -> px[b*49+ag][576] bf16 ----------
__global__ __launch_bounds__(256) void k_poolx(const u16* __restrict__ xb, u16* __restrict__ px) {
    const int t = threadIdx.x;
    const int b = blockIdx.x / 7, p1 = blockIdx.x % 7;
    for (int task = t; task < 504; task += 256) {
        int p2 = task / 72, c8 = task - p2 * 72;
        const u16* base = xb + ((size_t)b * NN + (p1 * 8) * 56 + p2 * 8) * CC + c8 * 8;
        float s[8] = {0.f, 0.f, 0.f, 0.f, 0.f, 0.f, 0.f, 0.f};
        for (int y = 0; y < 8; ++y)
#pragma unroll
            for (int x = 0; x < 8; ++x) {
                u16x8 v = *(const u16x8*)(base + (size_t)(y * 56 + x) * CC);
#pragma unroll
                for (int j = 0; j < 8; j++) s[j] += bf2f(v[j]);
            }
        u16x8 o;
#pragma unroll
        for (int j = 0; j < 8; j++) o[j] = f2bf(s[j] * 0.015625f);
        *(u16x8*)(px + (size_t)(b * AGN + p1 * 7 + p2) * CC + c8 * 8) = o;
    }
}

// ---------- stage A (MFMA): S^T = mfma(K, a), online softmax per agent-col, PV = mfma(P, V^T) ----------
__global__ __launch_bounds__(256) void k_stageA(const u16* __restrict__ Kp, const u16* __restrict__ Vp,
                                                const float* __restrict__ a_f, const float* __restrict__ b1,
                                                float* __restrict__ part) {
    const int t = threadIdx.x, lane = t & 63, w = t >> 6;
    const int c = lane & 15, g = lane >> 4;
    const int bh = blockIdx.y, b = bh >> 3, h = bh & 7;
    const int chunk = blockIdx.x;                        // 0..5
    const int t0 = (chunk == 0) ? 0 : 9 + 8 * (chunk - 1);
    const int ntile = (chunk == 0) ? 9 : 8;

    __shared__ u16 A_lds[64][104];
    __shared__ u16 K_lds[64][104];
    __shared__ u16 Vt[80][72];
    __shared__ u16 P_lds[64][72];

    for (int i = t; i < 64 * 104; i += 256) {
        int r = i / 104, cc = i - r * 104;
        if (cc >= 72 || r >= 49) A_lds[r][cc] = 0;
        if (cc >= 72) K_lds[r][cc] = 0;
    }
    for (int i = t; i < 8 * 72; i += 256) Vt[72 + i / 72][i % 72] = 0;
    for (int i = t; i < 49 * 72; i += 256) {
        int r = i / 72, d = i - r * 72;
        A_lds[r][d] = f2bf(a_f[(size_t)(b * 49 + r) * CC + h * 72 + d] * SCALE);
    }
    __syncthreads();

    bf16x8 bfA[3];
#pragma unroll
    for (int ks = 0; ks < 3; ++ks) bfA[ks] = *(const bf16x8*)&A_lds[16 * w + c][8 * g + 32 * ks];

    float m_run = -1e30f, l_run = 0.f;
    f32x4 acc[5];
#pragma unroll
    for (int dt = 0; dt < 5; ++dt) acc[dt] = (f32x4)0.f;

    const u16* kb = Kp + ((size_t)(b * 8 + h) * NN + t0 * 64) * 72;
    const u16* vb = Vp + ((size_t)(b * 8 + h) * NN + t0 * 64) * 72;
    const int arow = min(16 * w + c, 48);

    for (int tile = 0; tile < ntile; ++tile) {
        for (int i = t; i < 576; i += 256) {
            int nl = i / 9, ch = i - nl * 9;
            u16x8 kd = *(const u16x8*)(kb + (size_t)tile * 4608 + i * 8);
            *(u16x8*)&K_lds[nl][ch * 8] = kd;
        }
        for (int i = t; i < 576; i += 256) {
            int ch = i >> 6, nl = i & 63;
            u16x8 vd = *(const u16x8*)(vb + (size_t)tile * 4608 + (nl * 9 + ch) * 8);
#pragma unroll
            for (int j = 0; j < 8; j++) Vt[ch * 8 + j][nl] = vd[j];
        }
        __syncthreads();

        f32x4 sT[4];
        const int nbase = (t0 + tile) * 64 + 4 * g;
#pragma unroll
        for (int nm = 0; nm < 4; ++nm) {
            f32x4 sv;
#pragma unroll
            for (int j = 0; j < 4; j++)
                sv[j] = b1[(size_t)(h * NN + nbase + 16 * nm + j) * AGN + arow];
#pragma unroll
            for (int ks = 0; ks < 3; ++ks) {
                bf16x8 af = *(const bf16x8*)&K_lds[16 * nm + c][8 * g + 32 * ks];
                sv = __builtin_amdgcn_mfma_f32_16x16x32_bf16(af, bfA[ks], sv, 0, 0, 0);
            }
            sT[nm] = sv;
        }

        float mt = sT[0][0];
#pragma unroll
        for (int nm = 0; nm < 4; ++nm)
#pragma unroll
            for (int j = 0; j < 4; j++) mt = fmaxf(mt, sT[nm][j]);
        mt = fmaxf(mt, __shfl_xor(mt, 16, 64));
        mt = fmaxf(mt, __shfl_xor(mt, 32, 64));
        float mnew = fmaxf(m_run, mt);
        float ps = 0.f;
#pragma unroll
        for (int nm = 0; nm < 4; ++nm) {
            float p0 = __expf(sT[nm][0] - mnew);
            float p1 = __expf(sT[nm][1] - mnew);
            float p2 = __expf(sT[nm][2] - mnew);
            float p3 = __expf(sT[nm][3] - mnew);
            ps += (p0 + p1) + (p2 + p3);
            unsigned pk01 = ((unsigned)f2bf(p1) << 16) | f2bf(p0);
            unsigned pk23 = ((unsigned)f2bf(p3) << 16) | f2bf(p2);
            unsigned* dst = (unsigned*)&P_lds[16 * w + c][16 * nm + 4 * g];
            dst[0] = pk01; dst[1] = pk23;
        }
        ps += __shfl_xor(ps, 16, 64);
        ps += __shfl_xor(ps, 32, 64);
        float rsc = __expf(m_run - mnew);
        l_run = l_run * rsc + ps;
        m_run = mnew;

        float rj[4];
#pragma unroll
        for (int j = 0; j < 4; j++) rj[j] = __shfl(rsc, 4 * g + j, 64);
        bf16x8 pa[2];
#pragma unroll
        for (int ks = 0; ks < 2; ++ks) pa[ks] = *(const bf16x8*)&P_lds[16 * w + c][8 * g + 32 * ks];
#pragma unroll
        for (int dt = 0; dt < 5; ++dt) {
            f32x4 a0 = acc[dt];
#pragma unroll
            for (int j = 0; j < 4; j++) a0[j] *= rj[j];
#pragma unroll
            for (int ks = 0; ks < 2; ++ks) {
                bf16x8 vf = *(const bf16x8*)&Vt[16 * dt + c][8 * g + 32 * ks];
                a0 = __builtin_amdgcn_mfma_f32_16x16x32_bf16(pa[ks], vf, a0, 0, 0, 0);
            }
            acc[dt] = a0;
        }
        __syncthreads();
    }

    const size_t pbase = (size_t)(bh * NCH + chunk) * (49 * 74);
#pragma unroll
    for (int dt = 0; dt < 5; ++dt) {
        int d = 16 * dt + c;
        if (d < 72) {
#pragma unroll
            for (int j = 0; j < 4; j++) {
                int agent = 16 * w + 4 * g + j;
                if (agent < 49) part[pbase + agent * 74 + d] = acc[dt][j];
            }
        }
    }
    if (g == 0) {
        int agent = 16 * w + c;
        if (agent < 49) {
            part[pbase + agent * 74 + 72] = m_run;
            part[pbase + agent * 74 + 73] = l_run;
        }
    }
}

// ---------- reduce partials across NCH chunks ----------
__global__ __launch_bounds__(256) void k_reduceA(const float* __restrict__ part, float* __restrict__ agv) {
    const int bh = blockIdx.x, t = threadIdx.x;
    const float* pb = part + (size_t)bh * NCH * (49 * 74);
    for (int idx = t; idx < 49 * 72; idx += 256) {
        int row = idx / 72, d = idx - row * 72;
        float m = -1e30f;
#pragma unroll
        for (int c = 0; c < NCH; c++) m = fmaxf(m, pb[c * (49 * 74) + row * 74 + 72]);
        float accv = 0.f, l = 0.f;
#pragma unroll
        for (int c = 0; c < NCH; c++) {
            const float* pc = pb + c * (49 * 74) + row * 74;
            float e = __expf(pc[72] - m);
            accv += pc[d] * e;
            l += pc[73] * e;
        }
        agv[(size_t)(bh * 49 + row) * 72 + d] = accv / l;
    }
}

// ---------- stage B (MFMA): S = mfma(agents, q) -> softmax over 49 -> PV = mfma(P^T, av^T), bf16 oat ----------
__global__ __launch_bounds__(256) void k_stageB(const u16* __restrict__ Qp, const float* __restrict__ a_f,
                                                const float* __restrict__ agv, const float* __restrict__ b2p,
                                                u16* __restrict__ oat) {
    const int t = threadIdx.x, lane = t & 63, w = t >> 6;
    const int c = lane & 15, g = lane >> 4;
    const int bh = blockIdx.y, b = bh >> 3, h = bh & 7;
    const int n0 = blockIdx.x * 256;

    __shared__ u16 A_lds[64][104];
    __shared__ u16 avT[80][72];
    __shared__ u16 Pt[4][64][76];

    for (int i = t; i < 64 * 104; i += 256) {
        int r = i / 104, cc = i - r * 104;
        if (cc >= 72 || r >= 49) A_lds[r][cc] = 0;
    }
    for (int i = t; i < 80 * 72; i += 256) ((u16*)avT)[i] = 0;
    __syncthreads();
    for (int i = t; i < 49 * 72; i += 256) {
        int r = i / 72, d = i - r * 72;
        A_lds[r][d] = f2bf(a_f[(size_t)(b * 49 + r) * CC + h * 72 + d] * SCALE);
        avT[d][r]   = f2bf(agv[(size_t)(bh * 49 + r) * 72 + d]);
    }
    __syncthreads();

    bf16x8 afr[4][3];
#pragma unroll
    for (int mt = 0; mt < 4; ++mt)
#pragma unroll
        for (int ks = 0; ks < 3; ++ks) afr[mt][ks] = *(const bf16x8*)&A_lds[16 * mt + c][8 * g + 32 * ks];

    const int nw0 = n0 + w * 64;
#pragma unroll
    for (int cg = 0; cg < 4; ++cg) {
        const int n = nw0 + 16 * cg + c;
        const int ne = min(n, NN - 1);
        const u16* qp = Qp + ((size_t)(b * 8 + h) * NN + ne) * 72;
        bf16x8 qf[3];
#pragma unroll
        for (int ks = 0; ks < 3; ++ks) qf[ks] = *(const bf16x8*)(qp + 8 * g + 32 * ks);
        const float* bp = b2p + (size_t)(h * NN + ne) * 64;
        f32x4 sv[4];
#pragma unroll
        for (int mt = 0; mt < 4; ++mt) sv[mt] = *(const f32x4*)(bp + 16 * mt + 4 * g);
#pragma unroll
        for (int ks = 0; ks < 3; ++ks)
#pragma unroll
            for (int mt = 0; mt < 4; ++mt)
                sv[mt] = __builtin_amdgcn_mfma_f32_16x16x32_bf16(afr[mt][ks], qf[ks], sv[mt], 0, 0, 0);
        float mx = sv[0][0];
#pragma unroll
        for (int mt = 0; mt < 4; ++mt)
#pragma unroll
            for (int j = 0; j < 4; j++) mx = fmaxf(mx, sv[mt][j]);
        mx = fmaxf(mx, __shfl_xor(mx, 16, 64));
        mx = fmaxf(mx, __shfl_xor(mx, 32, 64));
        float ps = 0.f;
#pragma unroll
        for (int mt = 0; mt < 4; ++mt) {
#pragma unroll
            for (int j = 0; j < 4; j++) { sv[mt][j] = __expf(sv[mt][j] - mx); ps += sv[mt][j]; }
        }
        ps += __shfl_xor(ps, 16, 64);
        ps += __shfl_xor(ps, 32, 64);
        float inv = 1.f / ps;
#pragma unroll
        for (int mt = 0; mt < 4; ++mt) {
            unsigned pk01 = ((unsigned)f2bf(sv[mt][1] * inv) << 16) | f2bf(sv[mt][0] * inv);
            unsigned pk23 = ((unsigned)f2bf(sv[mt][3] * inv) << 16) | f2bf(sv[mt][2] * inv);
            unsigned* dst = (unsigned*)&Pt[w][16 * cg + c][16 * mt + 4 * g];
            dst[0] = pk01; dst[1] = pk23;
        }
    }
    bf16x8 vfr[5][2];
#pragma unroll
    for (int dt = 0; dt < 5; ++dt)
#pragma unroll
        for (int ks = 0; ks < 2; ++ks) vfr[dt][ks] = *(const bf16x8*)&avT[16 * dt + c][8 * g + 32 * ks];
#pragma unroll
    for (int rt = 0; rt < 4; ++rt) {
        bf16x8 pf[2];
#pragma unroll
        for (int ks = 0; ks < 2; ++ks) pf[ks] = *(const bf16x8*)&Pt[w][16 * rt + c][8 * g + 32 * ks];
#pragma unroll
        for (int dt = 0; dt < 5; ++dt) {
            f32x4 a0 = (f32x4)0.f;
            a0 = __builtin_amdgcn_mfma_f32_16x16x32_bf16(pf[0], vfr[dt][0], a0, 0, 0, 0);
            a0 = __builtin_amdgcn_mfma_f32_16x16x32_bf16(pf[1], vfr[dt][1], a0, 0, 0, 0);
            int dd = 16 * dt + c;
            if (dd < 72) {
#pragma unroll
                for (int j = 0; j < 4; j++) {
                    int nn2 = nw0 + 16 * rt + 4 * g + j;
                    if (nn2 < NN) oat[((size_t)b * NN + nn2) * CC + h * 72 + dd] = f2bf(a0[j]);
                }
            }
        }
    }
}

// ---------- depthwise 3x3 conv + affine + relu + add (reg-resident weights) ----------
__global__ __launch_bounds__(576) void k_conv(const u16* __restrict__ Vp, const u16* __restrict__ oat,
                                              const float* __restrict__ w, const float* __restrict__ gamma,
                                              const float* __restrict__ beta, u16* __restrict__ pre) {
    const int t = threadIdx.x;
    const int g8 = t % 72;
    const int p  = t / 72;
    const int c0 = g8 * 8;
    const int hh = c0 / 72, dl = c0 - hh * 72;

    __shared__ float wlds[CC * 9];
    __shared__ float glds[CC], blds[CC];
    for (int i = t; i < CC * 9; i += 576) wlds[i] = w[i];
    glds[t < CC ? t : 0] = gamma[t < CC ? t : 0];
    blds[t < CC ? t : 0] = beta[t < CC ? t : 0];
    __syncthreads();

    float wv[8][9], gm[8], bt[8];
#pragma unroll
    for (int j = 0; j < 8; j++) {
#pragma unroll
        for (int tap = 0; tap < 9; tap++) wv[j][tap] = wlds[(c0 + j) * 9 + tap];
        gm[j] = glds[c0 + j]; bt[j] = blds[c0 + j];
    }

    for (int pt = blockIdx.x * 8 + p; pt < BB * NN; pt += gridDim.x * 8) {
        int b = pt / NN, n = pt - b * NN;
        int y = n / 56, x = n % 56;
        const u16* vbase = Vp + ((size_t)(b * 8 + hh) * NN) * 72 + dl;
        float a[8] = {0.f, 0.f, 0.f, 0.f, 0.f, 0.f, 0.f, 0.f};
#pragma unroll
        for (int dy = -1; dy <= 1; ++dy) {
            int yy = y + dy; if (yy < 0 || yy > 55) continue;
#pragma unroll
            for (int dx = -1; dx <= 1; ++dx) {
                int xx = x + dx; if (xx < 0 || xx > 55) continue;
                u16x8 vv = *(const u16x8*)(vbase + (size_t)(yy * 56 + xx) * 72);
                int tap = (dy + 1) * 3 + (dx + 1);
#pragma unroll
                for (int j = 0; j < 8; j++) a[j] += bf2f(vv[j]) * wv[j][tap];
            }
        }
        u16x8 ov = *(const u16x8*)(oat + (size_t)pt * CC + c0);
        u16x8 rr;
#pragma unroll
        for (int j = 0; j < 8; j++)
            rr[j] = f2bf(bf2f(ov[j]) + fmaxf(a[j] * gm[j] + bt[j], 0.f));
        *(u16x8*)(pre + (size_t)pt * CC + c0) = rr;
    }
}

// ---------- launch ----------
extern "C" void kernel_launch(void* const* d_in, const int* in_sizes, int n_in,
                              void* d_out, int out_size, void* d_ws, size_t ws_size,
                              hipStream_t stream) {
    const float* x     = (const float*)d_in[0];
    const float* Wq    = (const float*)d_in[1];
    const float* Wkv   = (const float*)d_in[2];
    const float* an_b  = (const float*)d_in[3];
    const float* na_b  = (const float*)d_in[4];
    const float* ah_b  = (const float*)d_in[5];
    const float* aw_b  = (const float*)d_in[6];
    const float* ha_b  = (const float*)d_in[7];
    const float* wa_b  = (const float*)d_in[8];
    const float* dwcw  = (const float*)d_in[9];
    const float* gam   = (const float*)d_in[10];
    const float* bet   = (const float*)d_in[11];
    const float* projw = (const float*)d_in[12];
    const float* projb = (const float*)d_in[13];
    float* out = (float*)d_out;

    char* ws = (char*)d_ws;
    u16* wbT  = (u16*)(ws + 0);                          //  1,990,656
    u16* wpT  = (u16*)(ws + 1990656);                    //    663,552
    u16* xb   = (u16*)(ws + 2654208);                    // 57,802,752 (reused: stageA partials, then 'pre')
    u16* Qp   = (u16*)(ws + 60456960);                   // 57,802,752
    u16* Kp   = (u16*)(ws + 118259712);                  // 57,802,752 (reused as bf16 oat after stageA)
    u16* Vp   = (u16*)(ws + 176062464);                  // 57,802,752
    float* af = (float*)(ws + 233865216);                //  1,806,336
    u16* px   = (u16*)(ws + 235671552);                  //    903,168 (agv region: disjoint lifetime)
    float* agv= (float*)(ws + 235671552);                //  1,806,336
    float* b1 = (float*)(ws + 237477888);                //  4,917,248  [h][n][49]
    float* b2p= (float*)(ws + 242395136);                //  6,422,528  [h][n][64] padded
    float* part = (float*)xb;                            // 11,139,072 (inside xb; dead before 'pre')
    u16* obuf = Kp;

    k_cast_x<<<28224, 256, 0, stream>>>(x, xb);
    k_prep_w<<<5184, 256, 0, stream>>>(Wq, Wkv, projw, wbT, wpT);
    k_bias1<<<4802, 256, 0, stream>>>(an_b, ah_b, aw_b, b1);
    k_bias2<<<6272, 256, 0, stream>>>(na_b, ha_b, wa_b, b2p);
    k_poolx<<<112, 256, 0, stream>>>(xb, px);
    k_gemm<2><<<dim3(5, 7), 256, 0, stream>>>(px, wbT, nullptr, nullptr, nullptr, af, nullptr, 784);
    k_gemm<0><<<dim3(14, 392), 256, 0, stream>>>(xb, wbT, Qp, Kp, Vp, nullptr, nullptr, BB * NN);
    k_stageA<<<dim3(NCH, 128), 256, 0, stream>>>(Kp, Vp, af, b1, part);
    k_reduceA<<<128, 256, 0, stream>>>(part, agv);
    k_stageB<<<dim3(13, 128), 256, 0, stream>>>(Qp, af, agv, b2p, obuf);
    k_conv<<<784, 576, 0, stream>>>(Vp, obuf, dwcw, gam, bet, xb /*pre*/);
    k_gemm<1><<<dim3(5, 392), 256, 0, stream>>>(xb /*pre*/, wpT, nullptr, nullptr, nullptr, out, projb, BB * NN);
}

// Round 10
// 441.996 us; speedup vs baseline: 1.1774x; 1.1774x over previous
//
#include <hip/hip_runtime.h>
#include <stdint.h>

// ---------- types ----------
typedef unsigned short u16;
typedef u16   u16x4 __attribute__((ext_vector_type(4)));
typedef u16   u16x8 __attribute__((ext_vector_type(8)));
typedef float f32x4 __attribute__((ext_vector_type(4)));
typedef __bf16 bf16x8 __attribute__((ext_vector_type(8)));

// ---------- constants ----------
#define BB    16
#define NN    3136
#define CC    576
#define HEADS 8
#define HD    72
#define AGN   49
#define NTOT  1728
#define NCH   6                      // stageA chunks: tiles {9,8,8,8,8,8} of 64 tokens -> 768 blocks = 3/CU
#define SCALE 0.1178511301977579f   // 72^-0.5

__device__ __forceinline__ u16 f2bf(float f) {
    unsigned u = __float_as_uint(f);
    return (u16)((u + 0x7fffu + ((u >> 16) & 1u)) >> 16);
}
__device__ __forceinline__ float bf2f(u16 u) {
    return __uint_as_float(((unsigned)u) << 16);
}

// ---------- cast x -> bf16 ----------
__global__ __launch_bounds__(256) void k_cast_x(const float* __restrict__ x, u16* __restrict__ xb) {
    size_t i = (size_t)blockIdx.x * 256 + threadIdx.x;
    f32x4 v = *(const f32x4*)(x + i * 4);
    u16x4 o; o[0] = f2bf(v[0]); o[1] = f2bf(v[1]); o[2] = f2bf(v[2]); o[3] = f2bf(v[3]);
    *(u16x4*)(xb + i * 4) = o;
}

// ---------- pack transposed bf16 weights ----------
__global__ __launch_bounds__(256) void k_prep_w(const float* __restrict__ Wq, const float* __restrict__ Wkv,
                                                const float* __restrict__ Wp,
                                                u16* __restrict__ wbT, u16* __restrict__ wpT) {
    int idx = blockIdx.x * 256 + threadIdx.x;
    if (idx < NTOT * CC) {
        int nn = idx / CC, kk = idx % CC;
        float v = (nn < CC) ? Wq[kk * CC + nn] : Wkv[kk * (2 * CC) + (nn - CC)];
        wbT[idx] = f2bf(v);
    } else {
        int j = idx - NTOT * CC;
        int nn = j / CC, kk = j % CC;
        wpT[j] = f2bf(Wp[kk * CC + nn]);
    }
}

// ---------- jax.image.resize 'linear' 7x7 -> 56x56 ----------
__device__ __forceinline__ float bilerp7(const float* __restrict__ g, int oy, int ox) {
    float cy = (oy - 3.5f) * 0.125f;
    float cx = (ox - 3.5f) * 0.125f;
    float fy0 = floorf(cy), fx0 = floorf(cx);
    float ty = cy - fy0, tx = cx - fx0;
    int iy0 = (int)fy0, ix0 = (int)fx0;
    int y0 = min(6, max(0, iy0)), y1 = min(6, max(0, iy0 + 1));
    int x0 = min(6, max(0, ix0)), x1 = min(6, max(0, ix0 + 1));
    float g00 = g[y0 * 7 + x0], g01 = g[y0 * 7 + x1];
    float g10 = g[y1 * 7 + x0], g11 = g[y1 * 7 + x1];
    return (1.f - ty) * ((1.f - tx) * g00 + tx * g01) + ty * ((1.f - tx) * g10 + tx * g11);
}

// bias1 layout: [h][n][49]
__global__ __launch_bounds__(256) void k_bias1(const float* __restrict__ an, const float* __restrict__ ah,
                                               const float* __restrict__ aw, float* __restrict__ b1) {
    int idx = blockIdx.x * 256 + threadIdx.x;
    int ag = idx % AGN; int r = idx / AGN; int n = r % NN; int h = r / NN;
    int y = n / 56, x = n % 56;
    float v = bilerp7(an + (h * AGN + ag) * 49, y, x);
    b1[idx] = v + ah[(h * AGN + ag) * 56 + y] + aw[(h * AGN + ag) * 56 + x];
}

// bias2 layout: [h][n][64] f32, pad ag>=49 with -1e30 (softmax kills them)
__global__ __launch_bounds__(256) void k_bias2(const float* __restrict__ na, const float* __restrict__ ha,
                                               const float* __restrict__ wa, float* __restrict__ b2p) {
    int idx = blockIdx.x * 256 + threadIdx.x;
    int ag = idx & 63; int r = idx >> 6; int n = r % NN; int h = r / NN;
    float v;
    if (ag < AGN) {
        int y = n / 56, x = n % 56;
        v = bilerp7(na + (h * AGN + ag) * 49, y, x)
          + ha[(h * 56 + y) * AGN + ag] + wa[(h * 56 + x) * AGN + ag];
    } else v = -1e30f;
    b2p[idx] = v;
}

// ---------- MFMA GEMM: A[M x 576] @ Bt[NB x 576]^T,  BM=128 BN=128 BK=64, XCD-swizzled ----------
template<int MODE>
__global__ __launch_bounds__(256) void k_gemm(const u16* __restrict__ A, const u16* __restrict__ Bt,
                                              u16* __restrict__ Qp, u16* __restrict__ Kp, u16* __restrict__ Vp,
                                              float* __restrict__ Cf, const float* __restrict__ bias,
                                              const int M) {
    const int NB = (MODE == 0) ? NTOT : CC;
    __shared__ u16 SMEM[2 * 128 * 64];
    u16* Asm = SMEM;
    u16* Bsm = SMEM + 128 * 64;
    const int t = threadIdx.x, lane = t & 63, wid = t >> 6;
    const int wm = wid & 1, wn = wid >> 1;
    const int nwg = gridDim.x * gridDim.y;
    const int id = blockIdx.y * gridDim.x + blockIdx.x;
    const int qq = nwg >> 3, rr = nwg & 7;
    const int xcd = id & 7, off = id >> 3;
    const int nid = (xcd < rr ? xcd * (qq + 1) : rr * (qq + 1) + (xcd - rr) * qq) + off;
    const int row0 = (nid / gridDim.x) * 128, col0 = (nid % gridDim.x) * 128;
    const int lr = lane & 15, lk = lane >> 4;
    f32x4 acc[4][4];
#pragma unroll
    for (int m = 0; m < 4; m++)
#pragma unroll
        for (int n2 = 0; n2 < 4; n2++) acc[m][n2] = (f32x4)0.f;

    for (int kt = 0; kt < 9; ++kt) {
        const int k0 = kt * 64;
#pragma unroll
        for (int it = 0; it < 4; ++it) {
            int flat = it * 256 + wid * 64 + lane;
            int r = flat >> 3, lc = (flat & 7) ^ (r & 7);
            int arow = min(row0 + r, M - 1);
            const u16* src = A + (size_t)arow * CC + k0 + lc * 8;
            __builtin_amdgcn_global_load_lds((const __attribute__((address_space(1))) void*)src,
                                             (__attribute__((address_space(3))) void*)(&Asm[(it * 256 + wid * 64) * 8]),
                                             16, 0, 0);
        }
#pragma unroll
        for (int it = 0; it < 4; ++it) {
            int flat = it * 256 + wid * 64 + lane;
            int r = flat >> 3, lc = (flat & 7) ^ (r & 7);
            int brow = min(col0 + r, NB - 1);
            const u16* src = Bt + (size_t)brow * CC + k0 + lc * 8;
            __builtin_amdgcn_global_load_lds((const __attribute__((address_space(1))) void*)src,
                                             (__attribute__((address_space(3))) void*)(&Bsm[(it * 256 + wid * 64) * 8]),
                                             16, 0, 0);
        }
        __syncthreads();
#pragma unroll
        for (int kk = 0; kk < 2; ++kk) {
            const int klocal2 = (kk * 32 + lk * 8) * 2;
            bf16x8 av[4], bv[4];
#pragma unroll
            for (int m = 0; m < 4; m++) {
                int row = wm * 64 + m * 16 + lr;
                av[m] = *(const bf16x8*)((const char*)Asm + row * 128 + (klocal2 ^ ((row & 7) << 4)));
            }
#pragma unroll
            for (int n2 = 0; n2 < 4; n2++) {
                int row = wn * 64 + n2 * 16 + lr;
                bv[n2] = *(const bf16x8*)((const char*)Bsm + row * 128 + (klocal2 ^ ((row & 7) << 4)));
            }
#pragma unroll
            for (int m = 0; m < 4; m++)
#pragma unroll
                for (int n2 = 0; n2 < 4; n2++)
                    acc[m][n2] = __builtin_amdgcn_mfma_f32_16x16x32_bf16(av[m], bv[n2], acc[m][n2], 0, 0, 0);
        }
        __syncthreads();
    }

    if (MODE == 0) {
#pragma unroll
        for (int n2 = 0; n2 < 4; n2++) {
            int cgl = col0 + wn * 64 + n2 * 16 + lr;
            if (cgl >= NB) continue;
            int which = cgl / 576;
            int rem = cgl - which * 576;
            int hh = rem / 72;
            int dd = rem - hh * 72;
            u16* dst = which == 0 ? Qp : (which == 1 ? Kp : Vp);
#pragma unroll
            for (int m = 0; m < 4; m++)
#pragma unroll
                for (int j = 0; j < 4; j++) {
                    int rgl = row0 + wm * 64 + m * 16 + lk * 4 + j;
                    int b = rgl / NN, n = rgl - b * NN;
                    dst[((size_t)(b * 8 + hh) * NN + n) * 72 + dd] = f2bf(acc[m][n2][j]);
                }
        }
    } else {
        float* Ef = (float*)SMEM;
#pragma unroll
        for (int ph = 0; ph < 4; ++ph) {
            if (wm == (ph >> 1)) {
#pragma unroll
                for (int mm = 0; mm < 2; mm++) {
                    int m = (ph & 1) * 2 + mm;
#pragma unroll
                    for (int n2 = 0; n2 < 4; n2++) {
                        int col = wn * 64 + n2 * 16 + lr;
                        float addv = (MODE == 1) ? bias[min(col0 + col, NB - 1)] : 0.f;
#pragma unroll
                        for (int j = 0; j < 4; j++)
                            Ef[(mm * 16 + lk * 4 + j) * 136 + col] = acc[m][n2][j] + addv;
                    }
                }
            }
            __syncthreads();
#pragma unroll
            for (int cc2 = 0; cc2 < 4; ++cc2) {
                int cidx = cc2 * 256 + t;
                int rl = cidx >> 5, colc = cidx & 31;
                int cgl = col0 + colc * 4;
                int rgl = row0 + ph * 32 + rl;
                if (cgl < NB && rgl < M) {
                    f32x4 v = *(const f32x4*)&Ef[rl * 136 + colc * 4];
                    *(f32x4*)(Cf + (size_t)rgl * 576 + cgl) = v;
                }
            }
            __syncthreads();
        }
    }
}

// ---------- pool x (8x8 windows) -> px[b*49+ag][576] bf16 ----------
__global__ __launch_bounds__(256) void k_poolx(const u16* __restrict__ xb, u16* __restrict__ px) {
    const int t = threadIdx.x;
    const int b = blockIdx.x / 7, p1 = blockIdx.x % 7;
    for (int task = t; task < 504; task += 256) {
        int p2 = task / 72, c8 = task - p2 * 72;
        const u16* base = xb + ((size_t)b * NN + (p1 * 8) * 56 + p2 * 8) * CC + c8 * 8;
        float s[8] = {0.f, 0.f, 0.f, 0.f, 0.f, 0.f, 0.f, 0.f};
        for (int y = 0; y < 8; ++y)
#pragma unroll
            for (int x = 0; x < 8; ++x) {
                u16x8 v = *(const u16x8*)(base + (size_t)(y * 56 + x) * CC);
#pragma unroll
                for (int j = 0; j < 8; j++) s[j] += bf2f(v[j]);
            }
        u16x8 o;
#pragma unroll
        for (int j = 0; j < 8; j++) o[j] = f2bf(s[j] * 0.015625f);
        *(u16x8*)(px + (size_t)(b * AGN + p1 * 7 + p2) * CC + c8 * 8) = o;
    }
}

// ---------- prep scaled agent frags: aSc[bh][64][96] bf16, zero-padded ----------
__global__ __launch_bounds__(256) void k_prepA(const float* __restrict__ a_f, u16* __restrict__ aSc) {
    int idx = blockIdx.x * 256 + threadIdx.x;            // 128*64*96 = 786432
    int d = idx % 96; int r = (idx / 96) & 63; int bh = idx / (96 * 64);
    int b = bh >> 3, h = bh & 7;
    u16 v = 0;
    if (r < AGN && d < HD) v = f2bf(a_f[((size_t)b * AGN + r) * CC + h * HD + d] * SCALE);
    aSc[idx] = v;
}

// ---------- stage A (MFMA): S^T = mfma(K, a), online softmax per agent-col, PV = mfma(P, V^T) ----------
__global__ __launch_bounds__(256) void k_stageA(const u16* __restrict__ Kp, const u16* __restrict__ Vp,
                                                const float* __restrict__ a_f, const float* __restrict__ b1,
                                                float* __restrict__ part) {
    const int t = threadIdx.x, lane = t & 63, w = t >> 6;
    const int c = lane & 15, g = lane >> 4;
    const int bh = blockIdx.y, b = bh >> 3, h = bh & 7;
    const int chunk = blockIdx.x;                        // 0..5
    const int t0 = (chunk == 0) ? 0 : 9 + 8 * (chunk - 1);
    const int ntile = (chunk == 0) ? 9 : 8;

    __shared__ u16 A_lds[64][104];
    __shared__ u16 K_lds[64][104];
    __shared__ u16 Vt[80][72];
    __shared__ u16 P_lds[64][72];

    for (int i = t; i < 64 * 104; i += 256) {
        int r = i / 104, cc = i - r * 104;
        if (cc >= 72 || r >= 49) A_lds[r][cc] = 0;
        if (cc >= 72) K_lds[r][cc] = 0;
    }
    for (int i = t; i < 8 * 72; i += 256) Vt[72 + i / 72][i % 72] = 0;
    for (int i = t; i < 49 * 72; i += 256) {
        int r = i / 72, d = i - r * 72;
        A_lds[r][d] = f2bf(a_f[(size_t)(b * 49 + r) * CC + h * 72 + d] * SCALE);
    }
    __syncthreads();

    bf16x8 bfA[3];
#pragma unroll
    for (int ks = 0; ks < 3; ++ks) bfA[ks] = *(const bf16x8*)&A_lds[16 * w + c][8 * g + 32 * ks];

    float m_run = -1e30f, l_run = 0.f;
    f32x4 acc[5];
#pragma unroll
    for (int dt = 0; dt < 5; ++dt) acc[dt] = (f32x4)0.f;

    const u16* kb = Kp + ((size_t)(b * 8 + h) * NN + t0 * 64) * 72;
    const u16* vb = Vp + ((size_t)(b * 8 + h) * NN + t0 * 64) * 72;
    const int arow = min(16 * w + c, 48);

    for (int tile = 0; tile < ntile; ++tile) {
        for (int i = t; i < 576; i += 256) {
            int nl = i / 9, ch = i - nl * 9;
            u16x8 kd = *(const u16x8*)(kb + (size_t)tile * 4608 + i * 8);
            *(u16x8*)&K_lds[nl][ch * 8] = kd;
        }
        for (int i = t; i < 576; i += 256) {
            int ch = i >> 6, nl = i & 63;
            u16x8 vd = *(const u16x8*)(vb + (size_t)tile * 4608 + (nl * 9 + ch) * 8);
#pragma unroll
            for (int j = 0; j < 8; j++) Vt[ch * 8 + j][nl] = vd[j];
        }
        __syncthreads();

        f32x4 sT[4];
        const int nbase = (t0 + tile) * 64 + 4 * g;
#pragma unroll
        for (int nm = 0; nm < 4; ++nm) {
            f32x4 sv;
#pragma unroll
            for (int j = 0; j < 4; j++)
                sv[j] = b1[(size_t)(h * NN + nbase + 16 * nm + j) * AGN + arow];
#pragma unroll
            for (int ks = 0; ks < 3; ++ks) {
                bf16x8 af = *(const bf16x8*)&K_lds[16 * nm + c][8 * g + 32 * ks];
                sv = __builtin_amdgcn_mfma_f32_16x16x32_bf16(af, bfA[ks], sv, 0, 0, 0);
            }
            sT[nm] = sv;
        }

        float mt = sT[0][0];
#pragma unroll
        for (int nm = 0; nm < 4; ++nm)
#pragma unroll
            for (int j = 0; j < 4; j++) mt = fmaxf(mt, sT[nm][j]);
        mt = fmaxf(mt, __shfl_xor(mt, 16, 64));
        mt = fmaxf(mt, __shfl_xor(mt, 32, 64));
        float mnew = fmaxf(m_run, mt);
        float ps = 0.f;
#pragma unroll
        for (int nm = 0; nm < 4; ++nm) {
            float p0 = __expf(sT[nm][0] - mnew);
            float p1 = __expf(sT[nm][1] - mnew);
            float p2 = __expf(sT[nm][2] - mnew);
            float p3 = __expf(sT[nm][3] - mnew);
            ps += (p0 + p1) + (p2 + p3);
            unsigned pk01 = ((unsigned)f2bf(p1) << 16) | f2bf(p0);
            unsigned pk23 = ((unsigned)f2bf(p3) << 16) | f2bf(p2);
            unsigned* dst = (unsigned*)&P_lds[16 * w + c][16 * nm + 4 * g];
            dst[0] = pk01; dst[1] = pk23;
        }
        ps += __shfl_xor(ps, 16, 64);
        ps += __shfl_xor(ps, 32, 64);
        float rsc = __expf(m_run - mnew);
        l_run = l_run * rsc + ps;
        m_run = mnew;

        float rj[4];
#pragma unroll
        for (int j = 0; j < 4; j++) rj[j] = __shfl(rsc, 4 * g + j, 64);
        bf16x8 pa[2];
#pragma unroll
        for (int ks = 0; ks < 2; ++ks) pa[ks] = *(const bf16x8*)&P_lds[16 * w + c][8 * g + 32 * ks];
#pragma unroll
        for (int dt = 0; dt < 5; ++dt) {
            f32x4 a0 = acc[dt];
#pragma unroll
            for (int j = 0; j < 4; j++) a0[j] *= rj[j];
#pragma unroll
            for (int ks = 0; ks < 2; ++ks) {
                bf16x8 vf = *(const bf16x8*)&Vt[16 * dt + c][8 * g + 32 * ks];
                a0 = __builtin_amdgcn_mfma_f32_16x16x32_bf16(pa[ks], vf, a0, 0, 0, 0);
            }
            acc[dt] = a0;
        }
        __syncthreads();
    }

    const size_t pbase = (size_t)(bh * NCH + chunk) * (49 * 74);
#pragma unroll
    for (int dt = 0; dt < 5; ++dt) {
        int d = 16 * dt + c;
        if (d < 72) {
#pragma unroll
            for (int j = 0; j < 4; j++) {
                int agent = 16 * w + 4 * g + j;
                if (agent < 49) part[pbase + agent * 74 + d] = acc[dt][j];
            }
        }
    }
    if (g == 0) {
        int agent = 16 * w + c;
        if (agent < 49) {
            part[pbase + agent * 74 + 72] = m_run;
            part[pbase + agent * 74 + 73] = l_run;
        }
    }
}

// ---------- reduce partials across NCH chunks -> avTg[bh][80][72] bf16 (zero-padded, transposed) ----------
__global__ __launch_bounds__(256) void k_reduceA(const float* __restrict__ part, u16* __restrict__ avTg) {
    const int bh = blockIdx.x, t = threadIdx.x;
    const float* pb = part + (size_t)bh * NCH * (49 * 74);
    u16* av = avTg + (size_t)bh * 80 * 72;
    for (int i = t; i < 80 * 72; i += 256) av[i] = 0;
    __syncthreads();
    for (int idx = t; idx < 49 * 72; idx += 256) {
        int row = idx / 72, d = idx - row * 72;
        float m = -1e30f;
#pragma unroll
        for (int c = 0; c < NCH; c++) m = fmaxf(m, pb[c * (49 * 74) + row * 74 + 72]);
        float accv = 0.f, l = 0.f;
#pragma unroll
        for (int c = 0; c < NCH; c++) {
            const float* pc = pb + c * (49 * 74) + row * 74;
            float e = __expf(pc[72] - m);
            accv += pc[d] * e;
            l += pc[73] * e;
        }
        av[d * 72 + row] = f2bf(accv / l);
    }
}

// ---------- stage B + conv fused (v2): frags from global; Pt pitch 88; PV swapped -> row-wise writeback ----------
__global__ __launch_bounds__(256) void k_stageBC(const u16* __restrict__ Qp, const u16* __restrict__ aSc,
                                                 const u16* __restrict__ avTg, const float* __restrict__ b2p,
                                                 const u16* __restrict__ Vp, const float* __restrict__ cw,
                                                 const float* __restrict__ gamma, const float* __restrict__ beta,
                                                 u16* __restrict__ pre) {
    const int t = threadIdx.x, lane = t & 63, w = t >> 6;
    const int c = lane & 15, g = lane >> 4;
    const int bh = blockIdx.y, b = bh >> 3, h = bh & 7;
    const int n0 = blockIdx.x * 256;

    __shared__ u16 Pt[4][64][88];                        // 45056 B: per-wave P [n][ag], then bf16 oat [n][d]
    __shared__ float wle[72 * 9];                        //  2592 B
    __shared__ float gle[72], ble[72];                   //   576 B

    for (int i = t; i < 648; i += 256) wle[i] = cw[h * 648 + i];
    if (t < 72) { gle[t] = gamma[h * 72 + t]; ble[t] = beta[h * 72 + t]; }

    // frag loads from small global buffers (L2-resident; 16B aligned)
    const u16* aB = aSc + (size_t)bh * 64 * 96;
    bf16x8 afr[4][3];
#pragma unroll
    for (int mt = 0; mt < 4; ++mt)
#pragma unroll
        for (int ks = 0; ks < 3; ++ks) afr[mt][ks] = *(const bf16x8*)(aB + (16 * mt + c) * 96 + 8 * g + 32 * ks);
    const u16* vB = avTg + (size_t)bh * 80 * 72;
    bf16x8 vfr[5][2];
#pragma unroll
    for (int dt = 0; dt < 5; ++dt)
#pragma unroll
        for (int ks = 0; ks < 2; ++ks) vfr[dt][ks] = *(const bf16x8*)(vB + (16 * dt + c) * 72 + 8 * g + 32 * ks);

    const int nw0 = n0 + w * 64;
    // ---- QK + softmax over 49 agents; P (normalized bf16) -> Pt[w][n-local][ag] ----
#pragma unroll
    for (int cg = 0; cg < 4; ++cg) {
        const int n = nw0 + 16 * cg + c;
        const int ne = min(n, NN - 1);
        const u16* qp = Qp + ((size_t)(b * 8 + h) * NN + ne) * 72;
        bf16x8 qf[3];
#pragma unroll
        for (int ks = 0; ks < 3; ++ks) qf[ks] = *(const bf16x8*)(qp + 8 * g + 32 * ks);  // k>=72 garbage x aSc-zero = 0
        const float* bp = b2p + (size_t)(h * NN + ne) * 64;
        f32x4 sv[4];
#pragma unroll
        for (int mt = 0; mt < 4; ++mt) sv[mt] = *(const f32x4*)(bp + 16 * mt + 4 * g);
#pragma unroll
        for (int ks = 0; ks < 3; ++ks)
#pragma unroll
            for (int mt = 0; mt < 4; ++mt)
                sv[mt] = __builtin_amdgcn_mfma_f32_16x16x32_bf16(afr[mt][ks], qf[ks], sv[mt], 0, 0, 0);
        float mx = sv[0][0];
#pragma unroll
        for (int mt = 0; mt < 4; ++mt)
#pragma unroll
            for (int j = 0; j < 4; j++) mx = fmaxf(mx, sv[mt][j]);
        mx = fmaxf(mx, __shfl_xor(mx, 16, 64));
        mx = fmaxf(mx, __shfl_xor(mx, 32, 64));
        float ps = 0.f;
#pragma unroll
        for (int mt = 0; mt < 4; ++mt) {
#pragma unroll
            for (int j = 0; j < 4; j++) { sv[mt][j] = __expf(sv[mt][j] - mx); ps += sv[mt][j]; }
        }
        ps += __shfl_xor(ps, 16, 64);
        ps += __shfl_xor(ps, 32, 64);
        float inv = 1.f / ps;
#pragma unroll
        for (int mt = 0; mt < 4; ++mt) {
            unsigned pk01 = ((unsigned)f2bf(sv[mt][1] * inv) << 16) | f2bf(sv[mt][0] * inv);
            unsigned pk23 = ((unsigned)f2bf(sv[mt][3] * inv) << 16) | f2bf(sv[mt][2] * inv);
            unsigned* dst = (unsigned*)&Pt[w][16 * cg + c][16 * mt + 4 * g];
            dst[0] = pk01; dst[1] = pk23;
        }
    }
    // ---- PV swapped: a0 = mfma(avT, P) -> lane holds O[d=16dt+4g+j][n=16rt+c]; row-wise u16x4 writeback ----
#pragma unroll
    for (int rt = 0; rt < 4; ++rt) {
        bf16x8 pf[2];
#pragma unroll
        for (int ks = 0; ks < 2; ++ks) pf[ks] = *(const bf16x8*)&Pt[w][16 * rt + c][8 * g + 32 * ks];
#pragma unroll
        for (int dt = 0; dt < 5; ++dt) {
            f32x4 a0 = (f32x4)0.f;
            a0 = __builtin_amdgcn_mfma_f32_16x16x32_bf16(vfr[dt][0], pf[0], a0, 0, 0, 0);
            a0 = __builtin_amdgcn_mfma_f32_16x16x32_bf16(vfr[dt][1], pf[1], a0, 0, 0, 0);
            int d0 = 16 * dt + 4 * g;
            if (d0 < 72) {
                u16x4 rr; rr[0] = f2bf(a0[0]); rr[1] = f2bf(a0[1]); rr[2] = f2bf(a0[2]); rr[3] = f2bf(a0[3]);
                *(u16x4*)&Pt[w][16 * rt + c][d0] = rr;
            }
        }
    }
    __syncthreads();

    // ---- conv phase: dwc3x3(V) affine relu + oat(LDS), write pre ----
    const u16* PtF = &Pt[0][0][0];
    const u16* vh = Vp + ((size_t)(b * 8 + h) * NN) * 72;
    for (int task = t; task < 256 * 9; task += 256) {
        int tl = task / 9, ch = task - tl * 9;
        int n = n0 + tl;
        if (n >= NN) continue;
        int y = n / 56, x = n % 56;
        float a[8] = {0.f, 0.f, 0.f, 0.f, 0.f, 0.f, 0.f, 0.f};
#pragma unroll
        for (int dy = -1; dy <= 1; ++dy) {
            int yy = y + dy; if (yy < 0 || yy > 55) continue;
#pragma unroll
            for (int dx = -1; dx <= 1; ++dx) {
                int xx = x + dx; if (xx < 0 || xx > 55) continue;
                u16x8 vv = *(const u16x8*)(vh + (size_t)(yy * 56 + xx) * 72 + ch * 8);
                int tap = (dy + 1) * 3 + (dx + 1);
#pragma unroll
                for (int j = 0; j < 8; j++) a[j] += bf2f(vv[j]) * wle[(ch * 8 + j) * 9 + tap];
            }
        }
        u16x8 ov = *(const u16x8*)&PtF[tl * 88 + ch * 8];
        u16x8 rr2;
#pragma unroll
        for (int j = 0; j < 8; j++)
            rr2[j] = f2bf(bf2f(ov[j]) + fmaxf(a[j] * gle[ch * 8 + j] + ble[ch * 8 + j], 0.f));
        *(u16x8*)(pre + ((size_t)b * NN + n) * CC + h * 72 + ch * 8) = rr2;
    }
}

// ---------- launch ----------
extern "C" void kernel_launch(void* const* d_in, const int* in_sizes, int n_in,
                              void* d_out, int out_size, void* d_ws, size_t ws_size,
                              hipStream_t stream) {
    const float* x     = (const float*)d_in[0];
    const float* Wq    = (const float*)d_in[1];
    const float* Wkv   = (const float*)d_in[2];
    const float* an_b  = (const float*)d_in[3];
    const float* na_b  = (const float*)d_in[4];
    const float* ah_b  = (const float*)d_in[5];
    const float* aw_b  = (const float*)d_in[6];
    const float* ha_b  = (const float*)d_in[7];
    const float* wa_b  = (const float*)d_in[8];
    const float* dwcw  = (const float*)d_in[9];
    const float* gam   = (const float*)d_in[10];
    const float* bet   = (const float*)d_in[11];
    const float* projw = (const float*)d_in[12];
    const float* projb = (const float*)d_in[13];
    float* out = (float*)d_out;

    char* ws = (char*)d_ws;
    u16* wbT  = (u16*)(ws + 0);                          //  1,990,656
    u16* wpT  = (u16*)(ws + 1990656);                    //    663,552
    u16* xb   = (u16*)(ws + 2654208);                    // 57,802,752 (reused: stageA partials, then 'pre')
    u16* Qp   = (u16*)(ws + 60456960);                   // 57,802,752
    u16* Kp   = (u16*)(ws + 118259712);                  // 57,802,752 (reused as aSc after stageA)
    u16* Vp   = (u16*)(ws + 176062464);                  // 57,802,752
    float* af = (float*)(ws + 233865216);                //  1,806,336
    u16* px   = (u16*)(ws + 235671552);                  //    903,168 (dead after gemm<2>)
    u16* avTg = (u16*)(ws + 235671552);                  //  1,474,560 (same region; disjoint lifetime)
    float* b1 = (float*)(ws + 237477888);                //  4,917,248  [h][n][49]
    float* b2p= (float*)(ws + 242395136);                //  6,422,528  [h][n][64] padded
    float* part = (float*)xb;                            // 11,139,072 (inside xb; dead before 'pre')
    u16* aSc = Kp;                                       //  1,572,864 (Kp dead after stageA)

    k_cast_x<<<28224, 256, 0, stream>>>(x, xb);
    k_prep_w<<<5184, 256, 0, stream>>>(Wq, Wkv, projw, wbT, wpT);
    k_bias1<<<4802, 256, 0, stream>>>(an_b, ah_b, aw_b, b1);
    k_bias2<<<6272, 256, 0, stream>>>(na_b, ha_b, wa_b, b2p);
    k_poolx<<<112, 256, 0, stream>>>(xb, px);
    k_gemm<2><<<dim3(5, 7), 256, 0, stream>>>(px, wbT, nullptr, nullptr, nullptr, af, nullptr, 784);
    k_gemm<0><<<dim3(14, 392), 256, 0, stream>>>(xb, wbT, Qp, Kp, Vp, nullptr, nullptr, BB * NN);
    k_stageA<<<dim3(NCH, 128), 256, 0, stream>>>(Kp, Vp, af, b1, part);
    k_reduceA<<<128, 256, 0, stream>>>(part, avTg);
    k_prepA<<<3072, 256, 0, stream>>>(af, aSc);
    k_stageBC<<<dim3(13, 128), 256, 0, stream>>>(Qp, aSc, avTg, b2p, Vp, dwcw, gam, bet, xb /*pre*/);
    k_gemm<1><<<dim3(5, 392), 256, 0, stream>>>(xb /*pre*/, wpT, nullptr, nullptr, nullptr, out, projb, BB * NN);
}